// Round 15
// baseline (215.632 us; speedup 1.0000x reference)
//
#include <hip/hip_runtime.h>
#include <stdint.h>

#define B_ 8
#define C_ 32
#define N_ 4096
#define KOUT 9
#define RPB 16      // rows (centers) per block; wave w selects row w
#define TPB 1024    // 16 waves; thread owns 4 contiguous j

typedef unsigned long long u64;
typedef unsigned int u32;

// monotone float->uint mapping: a<b  <=>  fkey(a)<fkey(b)  (pack time only)
__device__ __forceinline__ u32 fkey(float f) {
    u32 u = __float_as_uint(f);
    return u ^ (u32)((((int)u) >> 31) | 0x80000000u);
}

// branchless insert of k into sorted L0<=..<=L5 (keep 6 smallest) — fallback only
__device__ __forceinline__ void ins6(u64 k, u64& L0, u64& L1, u64& L2,
                                     u64& L3, u64& L4, u64& L5) {
    bool lt0 = k < L0, lt1 = k < L1, lt2 = k < L2,
         lt3 = k < L3, lt4 = k < L4, lt5 = k < L5;
    L5 = lt4 ? L4 : (lt5 ? k : L5);
    L4 = lt3 ? L3 : (lt4 ? k : L4);
    L3 = lt2 ? L2 : (lt3 ? k : L3);
    L2 = lt1 ? L1 : (lt2 ? k : L2);
    L1 = lt0 ? L0 : (lt1 ? k : L1);
    L0 = lt0 ? k : L0;
}

// sq[b,n] = np.sum(pts*pts, -1), numpy pairwise 8-acc pattern (bit-exact, proven R1)
__global__ __launch_bounds__(256) void sq_kernel(const float* __restrict__ x,
                                                 float* __restrict__ sq) {
#pragma clang fp contract(off)
    int gid = blockIdx.x * 256 + threadIdx.x;
    int b = gid >> 12, n = gid & (N_ - 1);
    const float* xp = x + (size_t)b * (C_ * N_) + n;
    float w[C_];
#pragma unroll
    for (int c = 0; c < C_; ++c) { float v = xp[(size_t)c * N_]; w[c] = v * v; }
    float r[8];
#pragma unroll
    for (int j = 0; j < 8; ++j) r[j] = w[j];
#pragma unroll
    for (int i = 8; i < 32; i += 8) {
#pragma unroll
        for (int j = 0; j < 8; ++j) r[j] = r[j] + w[i + j];
    }
    sq[gid] = ((r[0] + r[1]) + (r[2] + r[3])) + ((r[4] + r[5]) + (r[6] + r[7]));
}

__global__ __launch_bounds__(TPB, 4) void knn_kernel(const float* __restrict__ x,
                                                     const float* __restrict__ sq,
                                                     int* __restrict__ out) {
#pragma clang fp contract(off)
    __shared__ float cenL[C_][RPB];      // 2 KB centers (fallback path only)
    __shared__ float mL[RPB][16][64];    // 64 KB per-(row, src-wave, lane) min key
    __shared__ u64 bufL[RPB][64];        // 8 KB candidate buffers
    __shared__ u32 cntL[RPB];
    __shared__ float tL[RPB];

    const int tid = threadIdx.x;
    const int b = blockIdx.x & 7;               // XCD-batch affinity (proven R2)
    const int i0 = (blockIdx.x >> 3) * RPB;
    const float* xb = x + (size_t)b * (C_ * N_);
    const float* sqb = sq + b * N_;

    if (tid < RPB * C_) {
        int r = tid & (RPB - 1), c = tid >> 4;
        cenL[c][r] = xb[(size_t)c * N_ + (i0 + r)];
    }
    __syncthreads();

    // ---- phase 1: thread t owns j = 4t + q (q=0..3); 16 rows share each load.
    // load:FMA ratio = 1/16 (vs 1/8 at RPB=8): 16 b128 loads per 2048 FMAs.
    // Centers via wave-uniform scalar loads (proven R13). acc[16][4] = 64 VGPR;
    // launch_bounds caps at 128 -> 4 waves/SIMD, 1 block/CU.
    float acc[RPB][4];
#pragma unroll
    for (int r = 0; r < RPB; ++r)
#pragma unroll
        for (int q = 0; q < 4; ++q) acc[r][q] = 0.0f;

    const int j0 = tid << 2;
#pragma unroll 1
    for (int cc = 0; cc < C_; cc += 4) {
        float4 v[4];                     // 4 b128 in flight
#pragma unroll
        for (int e = 0; e < 4; ++e)
            v[e] = *(const float4*)(xb + (size_t)(cc + e) * N_ + j0);
#pragma unroll
        for (int e = 0; e < 4; ++e) {
            const float* cg = xb + (size_t)(cc + e) * N_ + i0;  // uniform address
            float ce[RPB];
#pragma unroll
            for (int r = 0; r < RPB; ++r) ce[r] = cg[r];        // scalar loads
            float vv[4] = {v[e].x, v[e].y, v[e].z, v[e].w};
            // numpy einsum chain: c ascending per (row, j) — bit-exactness invariant
#pragma unroll
            for (int r = 0; r < RPB; ++r)
#pragma unroll
                for (int q = 0; q < 4; ++q)
                    acc[r][q] = __builtin_fmaf(ce[r], vv[q], acc[r][q]);
        }
    }

    // ---- epilogue: float keys; (sq_i - 2*inner) + sq_j, each op rounded once.
    // Distances never -0.0 / NaN / Inf -> float compares == fkey order (R13).
    const int wv = tid >> 6, lane = tid & 63;
    float fk[RPB][4];
    {
        float4 s0 = *(const float4*)(sqb + j0);
        float sj[4] = {s0.x, s0.y, s0.z, s0.w};
#pragma unroll
        for (int r = 0; r < RPB; ++r) {
            float sqi = sqb[i0 + r];
#pragma unroll
            for (int q = 0; q < 4; ++q)
                fk[r][q] = (sqi - 2.0f * acc[r][q]) + sj[q];
        }
    }

    // per-thread per-row min -> mL (kept in regs for scan-B early skip)
    float minr[RPB];
#pragma unroll
    for (int r = 0; r < RPB; ++r) {
        float mn = fminf(fminf(fk[r][0], fk[r][1]), fminf(fk[r][2], fk[r][3]));
        minr[r] = mn;
        mL[r][wv][lane] = mn;
    }
    if (tid < RPB) cntL[tid] = 0;
    __syncthreads();

    // ---- T for row wv: partition(lane) = 16 threads x 4 j = 64 j's (disjoint).
    // T = 18th-smallest partition min => >=18 distinct keys <= T => top-17
    // subset of {key <= T}; cnt >= 18. (Partition-shape-independent guarantee.)
    {
        float mn = mL[wv][0][lane];
#pragma unroll
        for (int s = 1; s < 16; ++s) mn = fminf(mn, mL[wv][s][lane]);
        float v32 = mn;
#pragma unroll
        for (int k = 2; k <= 64; k <<= 1) {
#pragma unroll
            for (int j = k >> 1; j >= 1; j >>= 1) {
                float pv = __shfl_xor(v32, j);
                bool keepMin = (((lane & j) == 0) == ((lane & k) == 0));
                float lo = v32 < pv ? v32 : pv;
                float hi = v32 < pv ? pv : v32;
                v32 = keepMin ? lo : hi;
            }
        }
        if (lane == 17) tL[wv] = v32;    // sorted[17] lives in lane 17
    }
    __syncthreads();

    // ---- scan B: append keys <= T[r] (fkey applied only at pack) ----
    {
#pragma unroll
        for (int r = 0; r < RPB; ++r) {
            float Tr = tL[r];
            if (minr[r] <= Tr) {         // vast majority of (thread,row) pairs skip
#pragma unroll
                for (int q = 0; q < 4; ++q) {
                    if (fk[r][q] <= Tr) {
                        u32 s = atomicAdd(&cntL[r], 1u);
                        if (s < 64) bufL[r][s] = ((u64)fkey(fk[r][q]) << 32) | (u32)(j0 + q);
                    }
                }
            }
        }
    }
    __syncthreads();

    // ---- wave wv: rank-by-counting selection on row wv's candidates ----
    {
        const int w = wv;
        const u32 cnt = cntL[w];
        const int row = b * N_ + i0 + w;
        if (cnt <= 64) {
            u64 myc = (lane < (int)cnt) ? bufL[w][lane] : ~0ull;
            u32 rank = 0;
            for (u32 m = 0; m < cnt; ++m) {
                u64 o = bufL[w][m];          // same-address broadcast read
                rank += (o < myc) ? 1u : 0u;
            }
            // dilated output = sorted positions 0,2,...,16 -> slot rank/2
            if (lane < (int)cnt && rank <= 16 && (rank & 1) == 0)
                out[row * KOUT + (rank >> 1)] = (int)((u32)myc & (N_ - 1));
            if (lane < KOUT)
                out[B_ * N_ * KOUT + row * KOUT + lane] = i0 + w;
        } else {
            // ---- fallback (P ~ e^-21 per row): recompute row bit-exactly + pop-2 ----
            const float sqw = sqb[i0 + w];
            u64 L0 = ~0ull, L1 = ~0ull, L2 = ~0ull, L3 = ~0ull, L4 = ~0ull, L5 = ~0ull;
#pragma unroll 1
            for (int m = 0; m < 64; ++m) {
                int j = lane + (m << 6);
                float a = 0.0f;
#pragma unroll 1
                for (int c = 0; c < C_; ++c)
                    a = __builtin_fmaf(cenL[c][w], xb[(size_t)c * N_ + j], a);
                float d = (sqw - 2.0f * a) + sqb[j];
                ins6(((u64)fkey(d) << 32) | (u32)j, L0, L1, L2, L3, L4, L5);
            }
            u64 lastPop = 0;
            u32 myw = 0;
#pragma unroll 1
            for (int r = 0; r < KOUT; ++r) {
                u64 a0 = L0, a1 = L1;
#pragma unroll
                for (int off = 32; off >= 1; off >>= 1) {
                    u64 b0 = __shfl_xor(a0, off);
                    u64 b1 = __shfl_xor(a1, off);
                    u64 lo = (a0 < b0) ? a0 : b0;
                    u64 hi = (a0 < b0) ? b0 : a0;
                    u64 m1 = (a1 < b1) ? a1 : b1;
                    a0 = lo;
                    a1 = (hi < m1) ? hi : m1;
                }
                if (lane == r) myw = (u32)a0;
                bool own0 = ((u32)a0 & 63) == (u32)lane;
                bool own1 = ((u32)a1 & 63) == (u32)lane;
                if (own0) { lastPop = a0; L0 = L1; L1 = L2; L2 = L3; L3 = L4; L4 = L5; L5 = ~0ull; }
                if (own1) { lastPop = a1; L0 = L1; L1 = L2; L2 = L3; L3 = L4; L4 = L5; L5 = ~0ull; }
                if ((own0 || own1) && L1 == ~0ull && r < KOUT - 1) {
                    L0 = L1 = L2 = L3 = L4 = L5 = ~0ull;
#pragma unroll 1
                    for (int m = 0; m < 64; ++m) {
                        int j = lane + (m << 6);
                        float a = 0.0f;
#pragma unroll 1
                        for (int c = 0; c < C_; ++c)
                            a = __builtin_fmaf(cenL[c][w], xb[(size_t)c * N_ + j], a);
                        float d = (sqw - 2.0f * a) + sqb[j];
                        u64 kk = ((u64)fkey(d) << 32) | (u32)j;
                        if (kk > lastPop) ins6(kk, L0, L1, L2, L3, L4, L5);
                    }
                }
            }
            if (lane < KOUT) {
                int o = row * KOUT + lane;
                out[o] = (int)(myw & (N_ - 1));
                out[B_ * N_ * KOUT + o] = i0 + w;
            }
        }
    }
}

extern "C" void kernel_launch(void* const* d_in, const int* in_sizes, int n_in,
                              void* d_out, int out_size, void* d_ws, size_t ws_size,
                              hipStream_t stream) {
    const float* x = (const float*)d_in[0];
    float* sq = (float*)d_ws;            // B*N floats = 128 KB
    int* out = (int*)d_out;

    hipLaunchKernelGGL(sq_kernel, dim3(B_ * N_ / 256), dim3(256), 0, stream, x, sq);
    hipLaunchKernelGGL(knn_kernel, dim3(B_ * N_ / RPB), dim3(TPB), 0, stream, x, sq, out);
}

// Round 16
// 182.290 us; speedup vs baseline: 1.1829x; 1.1829x over previous
//
#include <hip/hip_runtime.h>
#include <stdint.h>

#define B_ 8
#define C_ 32
#define N_ 4096
#define KOUT 9
#define RPB 8       // rows (centers) per block; wave w selects row w
#define TPB 512     // 8 waves

typedef unsigned long long u64;
typedef unsigned int u32;

// monotone float->uint mapping: a<b  <=>  fkey(a)<fkey(b)  (pack time only)
__device__ __forceinline__ u32 fkey(float f) {
    u32 u = __float_as_uint(f);
    return u ^ (u32)((((int)u) >> 31) | 0x80000000u);
}

// branchless insert of k into sorted L0<=..<=L5 (keep 6 smallest) — fallback only
__device__ __forceinline__ void ins6(u64 k, u64& L0, u64& L1, u64& L2,
                                     u64& L3, u64& L4, u64& L5) {
    bool lt0 = k < L0, lt1 = k < L1, lt2 = k < L2,
         lt3 = k < L3, lt4 = k < L4, lt5 = k < L5;
    L5 = lt4 ? L4 : (lt5 ? k : L5);
    L4 = lt3 ? L3 : (lt4 ? k : L4);
    L3 = lt2 ? L2 : (lt3 ? k : L3);
    L2 = lt1 ? L1 : (lt2 ? k : L2);
    L1 = lt0 ? L0 : (lt1 ? k : L1);
    L0 = lt0 ? k : L0;
}

// sq[b,n] = np.sum(pts*pts, -1), numpy pairwise 8-acc pattern (bit-exact, proven R1)
__global__ __launch_bounds__(256) void sq_kernel(const float* __restrict__ x,
                                                 float* __restrict__ sq) {
#pragma clang fp contract(off)
    int gid = blockIdx.x * 256 + threadIdx.x;
    int b = gid >> 12, n = gid & (N_ - 1);
    const float* xp = x + (size_t)b * (C_ * N_) + n;
    float w[C_];
#pragma unroll
    for (int c = 0; c < C_; ++c) { float v = xp[(size_t)c * N_]; w[c] = v * v; }
    float r[8];
#pragma unroll
    for (int j = 0; j < 8; ++j) r[j] = w[j];
#pragma unroll
    for (int i = 8; i < 32; i += 8) {
#pragma unroll
        for (int j = 0; j < 8; ++j) r[j] = r[j] + w[i + j];
    }
    sq[gid] = ((r[0] + r[1]) + (r[2] + r[3])) + ((r[4] + r[5]) + (r[6] + r[7]));
}

__global__ __launch_bounds__(TPB, 4) void knn_kernel(const float* __restrict__ x,
                                                     const float* __restrict__ sq,
                                                     int* __restrict__ out) {
#pragma clang fp contract(off)
    __shared__ float cenL[C_][RPB];      // 1 KB centers (fallback path only)
    __shared__ float mL[RPB][8][64];     // 16 KB per-(row, src-wave, lane) min key (f32)
    __shared__ u64 bufL[RPB][64];        // 4 KB candidate buffers
    __shared__ u32 cntL[RPB];
    __shared__ float tL[RPB];

    const int tid = threadIdx.x;
    const int b = blockIdx.x & 7;               // XCD-batch affinity (proven R2)
    const int i0 = (blockIdx.x >> 3) * RPB;
    const float* xb = x + (size_t)b * (C_ * N_);
    const float* sqb = sq + b * N_;

    if (tid < RPB * C_) {
        int r = tid & (RPB - 1), c = tid >> 3;
        cenL[c][r] = xb[(size_t)c * N_ + (i0 + r)];
    }
    __syncthreads();

    // ---- phase 1 (R13 verbatim): thread t owns j(q) = ((q>>2)<<11) + 4t + (q&3).
    // Centers via wave-uniform scalar loads; VGPR budget 64 (8-waves/SIMD cliff).
    float acc[RPB][8];                   // [row][q], all indices static
#pragma unroll
    for (int r = 0; r < RPB; ++r)
#pragma unroll
        for (int q = 0; q < 8; ++q) acc[r][q] = 0.0f;

    const int j0 = tid << 2;
#pragma unroll 1
    for (int cc = 0; cc < C_; cc += 4) {
        float4 v0[4], v1[4];             // hoisted loads: 8 b128 in flight
#pragma unroll
        for (int e = 0; e < 4; ++e) {
            const float* xc = xb + (size_t)(cc + e) * N_;
            v0[e] = *(const float4*)(xc + j0);
            v1[e] = *(const float4*)(xc + 2048 + j0);
        }
#pragma unroll
        for (int e = 0; e < 4; ++e) {
            const float* cg = xb + (size_t)(cc + e) * N_ + i0;  // uniform address
            float ce[8];
#pragma unroll
            for (int r = 0; r < RPB; ++r) ce[r] = cg[r];        // scalar loads
            float vv[8] = {v0[e].x, v0[e].y, v0[e].z, v0[e].w,
                           v1[e].x, v1[e].y, v1[e].z, v1[e].w};
            // numpy einsum chain: c ascending per (row, j) — bit-exactness invariant
#pragma unroll
            for (int r = 0; r < RPB; ++r)
#pragma unroll
                for (int q = 0; q < 8; ++q)
                    acc[r][q] = __builtin_fmaf(ce[r], vv[q], acc[r][q]);
        }
    }

    // ---- epilogue: float keys. numpy computes (sqi - 2*inner) + sqj with
    // 2*inner exact, sub rounded once: fmaf(-2, a, sqi) is the same single
    // rounding of the same exact value -> bit-identical, one op cheaper.
    // Distances never -0.0 / NaN / Inf -> float compares == fkey order (R13).
    const int wv = tid >> 6, lane = tid & 63;
    float fk[RPB][8];
    {
        float4 s0 = *(const float4*)(sqb + j0);
        float4 s1 = *(const float4*)(sqb + 2048 + j0);
        float sj[8] = {s0.x, s0.y, s0.z, s0.w, s1.x, s1.y, s1.z, s1.w};
#pragma unroll
        for (int r = 0; r < RPB; ++r) {
            float sqi = sqb[i0 + r];
#pragma unroll
            for (int q = 0; q < 8; ++q)
                fk[r][q] = __builtin_fmaf(-2.0f, acc[r][q], sqi) + sj[q];
        }
    }

    // per-thread per-row min -> mL (kept in regs for scan-B early skip)
    float minr[RPB];
#pragma unroll
    for (int r = 0; r < RPB; ++r) {
        float mn = fk[r][0];
#pragma unroll
        for (int q = 1; q < 8; ++q) mn = fminf(mn, fk[r][q]);
        minr[r] = mn;
        mL[r][wv][lane] = mn;
    }
    if (tid < RPB) cntL[tid] = 0;
    __syncthreads();

    // ---- T for row wv: partition(lane) = 8 threads x 8 j = 64 j's.
    // T = 18th-smallest partition min => >=18 distinct keys <= T => top-17
    // subset of {key <= T}; cnt >= 18. (Guarantee proven R9/R10.)
    {
        float mn = mL[wv][0][lane];
#pragma unroll
        for (int s = 1; s < 8; ++s) mn = fminf(mn, mL[wv][s][lane]);
        float v32 = mn;
#pragma unroll
        for (int k = 2; k <= 64; k <<= 1) {
#pragma unroll
            for (int j = k >> 1; j >= 1; j >>= 1) {
                float pv = __shfl_xor(v32, j);
                bool keepMin = (((lane & j) == 0) == ((lane & k) == 0));
                float lo = v32 < pv ? v32 : pv;
                float hi = v32 < pv ? pv : v32;
                v32 = keepMin ? lo : hi;
            }
        }
        if (lane == 17) tL[wv] = v32;    // sorted[17] lives in lane 17
    }
    __syncthreads();

    // ---- scan B: append keys <= T[r] (fkey applied only at pack) ----
    {
#pragma unroll
        for (int r = 0; r < RPB; ++r) {
            float Tr = tL[r];
            if (minr[r] <= Tr) {         // ~96% of (thread,row) pairs skip
#pragma unroll
                for (int q = 0; q < 8; ++q) {
                    if (fk[r][q] <= Tr) {
                        int jq = ((q >> 2) << 11) + j0 + (q & 3);
                        u32 s = atomicAdd(&cntL[r], 1u);
                        if (s < 64) bufL[r][s] = ((u64)fkey(fk[r][q]) << 32) | (u32)jq;
                    }
                }
            }
        }
    }
    __syncthreads();

    // ---- wave wv: rank-by-counting selection on row wv's candidates ----
    {
        const int w = wv;
        const u32 cnt = cntL[w];
        const int row = b * N_ + i0 + w;
        if (cnt <= 64) {
            u64 myc = (lane < (int)cnt) ? bufL[w][lane] : ~0ull;
            u32 rank = 0;
            for (u32 m = 0; m < cnt; ++m) {
                u64 o = bufL[w][m];          // same-address broadcast read
                rank += (o < myc) ? 1u : 0u;
            }
            // dilated output = sorted positions 0,2,...,16 -> slot rank/2
            if (lane < (int)cnt && rank <= 16 && (rank & 1) == 0)
                out[row * KOUT + (rank >> 1)] = (int)((u32)myc & (N_ - 1));
            if (lane < KOUT)
                out[B_ * N_ * KOUT + row * KOUT + lane] = i0 + w;
        } else {
            // ---- fallback (P ~ e^-21 per row): R7 proven scan + pop-2 path ----
            const float sqw = sqb[i0 + w];
            u64 L0 = ~0ull, L1 = ~0ull, L2 = ~0ull, L3 = ~0ull, L4 = ~0ull, L5 = ~0ull;
#pragma unroll 1
            for (int m = 0; m < 64; ++m) {
                int j = lane + (m << 6);
                float a = 0.0f;
#pragma unroll 1
                for (int c = 0; c < C_; ++c)
                    a = __builtin_fmaf(cenL[c][w], xb[(size_t)c * N_ + j], a);
                float d = __builtin_fmaf(-2.0f, a, sqw) + sqb[j];
                ins6(((u64)fkey(d) << 32) | (u32)j, L0, L1, L2, L3, L4, L5);
            }
            u64 lastPop = 0;
            u32 myw = 0;
#pragma unroll 1
            for (int r = 0; r < KOUT; ++r) {
                u64 a0 = L0, a1 = L1;
#pragma unroll
                for (int off = 32; off >= 1; off >>= 1) {
                    u64 b0 = __shfl_xor(a0, off);
                    u64 b1 = __shfl_xor(a1, off);
                    u64 lo = (a0 < b0) ? a0 : b0;
                    u64 hi = (a0 < b0) ? b0 : a0;
                    u64 m1 = (a1 < b1) ? a1 : b1;
                    a0 = lo;
                    a1 = (hi < m1) ? hi : m1;
                }
                if (lane == r) myw = (u32)a0;
                bool own0 = ((u32)a0 & 63) == (u32)lane;
                bool own1 = ((u32)a1 & 63) == (u32)lane;
                if (own0) { lastPop = a0; L0 = L1; L1 = L2; L2 = L3; L3 = L4; L4 = L5; L5 = ~0ull; }
                if (own1) { lastPop = a1; L0 = L1; L1 = L2; L2 = L3; L3 = L4; L4 = L5; L5 = ~0ull; }
                if ((own0 || own1) && L1 == ~0ull && r < KOUT - 1) {
                    L0 = L1 = L2 = L3 = L4 = L5 = ~0ull;
#pragma unroll 1
                    for (int m = 0; m < 64; ++m) {
                        int j = lane + (m << 6);
                        float a = 0.0f;
#pragma unroll 1
                        for (int c = 0; c < C_; ++c)
                            a = __builtin_fmaf(cenL[c][w], xb[(size_t)c * N_ + j], a);
                        float d = __builtin_fmaf(-2.0f, a, sqw) + sqb[j];
                        u64 kk = ((u64)fkey(d) << 32) | (u32)j;
                        if (kk > lastPop) ins6(kk, L0, L1, L2, L3, L4, L5);
                    }
                }
            }
            if (lane < KOUT) {
                int o = row * KOUT + lane;
                out[o] = (int)(myw & (N_ - 1));
                out[B_ * N_ * KOUT + o] = i0 + w;
            }
        }
    }
}

extern "C" void kernel_launch(void* const* d_in, const int* in_sizes, int n_in,
                              void* d_out, int out_size, void* d_ws, size_t ws_size,
                              hipStream_t stream) {
    const float* x = (const float*)d_in[0];
    float* sq = (float*)d_ws;            // B*N floats = 128 KB
    int* out = (int*)d_out;

    hipLaunchKernelGGL(sq_kernel, dim3(B_ * N_ / 256), dim3(256), 0, stream, x, sq);
    hipLaunchKernelGGL(knn_kernel, dim3(B_ * N_ / RPB), dim3(TPB), 0, stream, x, sq, out);
}